// Round 3
// baseline (664.978 us; speedup 1.0000x reference)
//
#include <hip/hip_runtime.h>
#include <stdint.h>

#define N_NODES 50000
#define N_EDGES 600000
#define NCLS    47

typedef __attribute__((ext_vector_type(8))) short short8;
typedef __attribute__((ext_vector_type(4))) float f32x4;

static __device__ __forceinline__ float bf2f(uint16_t h) {
    union { uint32_t u; float f; } c; c.u = ((uint32_t)h) << 16; return c.f;
}
static __device__ __forceinline__ uint16_t f2bf(float f) {
    union { float f; uint32_t u; } c; c.f = f;
    uint32_t u = c.u;
    return (uint16_t)((u + 0x7fffu + ((u >> 16) & 1u)) >> 16); // RNE
}
// split f32 -> bf16 hi + bf16 lo (v ~= hi + lo, err ~2^-18 rel)
static __device__ __forceinline__ void cvt_hilo8(const float* p, short8& hi, short8& lo) {
#pragma unroll
    for (int j = 0; j < 8; ++j) {
        float v = p[j];
        uint16_t h = f2bf(v);
        float r = v - bf2f(h);
        hi[j] = (short)h;
        lo[j] = (short)f2bf(r);
    }
}

// ------------------------- edge_index canonicalize (int64-or-int32 -> int32)
__global__ __launch_bounds__(256) void k_cvt_idx(const int* __restrict__ ei,
                                                 int* __restrict__ src,
                                                 int* __restrict__ dst) {
    __shared__ int is64;
    if (threadIdx.x == 0) {
        int z = 0;
        for (int i = 1; i < 256; i += 2) z |= ei[i];
        is64 = (z == 0) ? 1 : 0;   // int64 node ids < 2^31: all hi-words zero
    }
    __syncthreads();
    int e = blockIdx.x * 256 + threadIdx.x;
    if (e < N_EDGES) {
        int s, d;
        if (is64) { s = ei[2 * e]; d = ei[2 * (N_EDGES + e)]; }
        else      { s = ei[e];     d = ei[N_EDGES + e]; }
        src[e] = min(max(s, 0), N_NODES - 1);
        dst[e] = min(max(d, 0), N_NODES - 1);
    }
}

// ---------------------------------------------------------------- degree
__global__ __launch_bounds__(256) void k_deg(const int* __restrict__ dst, int* __restrict__ deg) {
    int e = blockIdx.x * 256 + threadIdx.x;
    if (e < N_EDGES) atomicAdd(&deg[dst[e]], 1);
}

// --------------------------------------------------- scan (1 block, 1024 thr)
__global__ __launch_bounds__(1024) void k_scan(const int* __restrict__ deg,
                                               int* __restrict__ row_start,
                                               int* __restrict__ fill,
                                               float* __restrict__ inv_deg) {
    __shared__ int psum[1024];
    const int CH = (N_NODES + 1023) / 1024; // 49
    int t = threadIdx.x;
    int lo = t * CH;
    int s = 0;
    for (int i = 0; i < CH; ++i) {
        int idx = lo + i;
        if (idx < N_NODES) s += deg[idx];
    }
    psum[t] = s;
    __syncthreads();
    for (int off = 1; off < 1024; off <<= 1) {
        int v = 0;
        if (t >= off) v = psum[t - off];
        __syncthreads();
        psum[t] += v;
        __syncthreads();
    }
    int base = psum[t] - s; // exclusive
    for (int i = 0; i < CH; ++i) {
        int idx = lo + i;
        if (idx < N_NODES) {
            int d = deg[idx];
            row_start[idx] = base;
            fill[idx] = base;
            inv_deg[idx] = 1.0f / (float)(d > 0 ? d : 1);
            base += d;
        }
    }
}

// ---------------------------------------------------------------- bucket fill
__global__ __launch_bounds__(256) void k_fill(const int* __restrict__ src,
                                              const int* __restrict__ dst,
                                              int* __restrict__ fill,
                                              int* __restrict__ elist) {
    int e = blockIdx.x * 256 + threadIdx.x;
    if (e < N_EDGES) {
        int pos = atomicAdd(&fill[dst[e]], 1);
        elist[pos] = src[e];
    }
}

// ----------------------------------------- mean aggregation (1 wave/node, f32)
__global__ __launch_bounds__(256) void k_agg(const float2* __restrict__ hm,
                                             const int* __restrict__ row_start,
                                             const int* __restrict__ degv,
                                             const float* __restrict__ inv_deg,
                                             const int* __restrict__ elist,
                                             float2* __restrict__ aggm) {
    int lane = threadIdx.x & 63;
    int node = blockIdx.x * 4 + (threadIdx.x >> 6);
    if (node >= N_NODES) return;
    int rs = row_start[node];
    int d = degv[node];
    float a0 = 0.f, a1 = 0.f;
    for (int i = 0; i < d; ++i) {
        int s = elist[rs + i];
        float2 w = hm[(size_t)s * 64 + lane];
        a0 += w.x;
        a1 += w.y;
    }
    float sc = inv_deg[node];
    aggm[(size_t)node * 64 + lane] = make_float2(a0 * sc, a1 * sc);
}

// -------------- weight prep: transpose W[k][col] -> img[col][k], bf16 hi + lo
// per matrix: hi image [npad*128], then lo image [npad*128]
__global__ __launch_bounds__(256) void k_prepw(const float* Wl0, const float* Wr0,
                                               const float* Wl1, const float* Wr1,
                                               const float* Wl2, const float* Wr2,
                                               uint16_t* __restrict__ img) {
    int b = blockIdx.x;
    const float* W; int ncol, npad; uint16_t* o;
    switch (b) {
        case 0: W = Wl0; ncol = 128; npad = 128; o = img;           break;
        case 1: W = Wr0; ncol = 128; npad = 128; o = img + 32768;   break;
        case 2: W = Wl1; ncol = 128; npad = 128; o = img + 65536;   break;
        case 3: W = Wr1; ncol = 128; npad = 128; o = img + 98304;   break;
        case 4: W = Wl2; ncol = 47;  npad = 48;  o = img + 131072;  break;
        default:W = Wr2; ncol = 47;  npad = 48;  o = img + 143360;  break;
    }
    int elems = npad * 128;
    for (int i = threadIdx.x; i < elems; i += 256) {
        int col = i % npad, k = i / npad;
        float v = (col < ncol) ? W[k * ncol + col] : 0.f;
        uint16_t h = f2bf(v);
        uint16_t l = f2bf(v - bf2f(h));
        int idx = col * 128 + k;
        o[idx] = h;
        o[idx + elems] = l;
    }
}

// ----------------------------- GEMM layers 0/1: out = relu(A1@Wl + A2@Wr + b)
// A1,A2: [N][128] f32.  wl/wr: transposed images, hi at +0, lo at +16384.
__global__ __launch_bounds__(256) void k_gemm(const float* __restrict__ A1,
                                              const float* __restrict__ A2,
                                              const uint16_t* __restrict__ wl,
                                              const uint16_t* __restrict__ wr,
                                              const float* __restrict__ bias,
                                              float* __restrict__ out) {
    int tid = threadIdx.x;
    int lane = tid & 63, wv = tid >> 6;
    int li = lane & 15, g4 = lane >> 4;
    int mrow = blockIdx.x * 128 + wv * 32 + li;
    int r0 = min(mrow, N_NODES - 1);
    int r1 = min(mrow + 16, N_NODES - 1);

    f32x4 acc[2][8];
#pragma unroll
    for (int m = 0; m < 2; ++m)
#pragma unroll
        for (int t = 0; t < 8; ++t) acc[m][t] = (f32x4){0.f, 0.f, 0.f, 0.f};

#pragma unroll
    for (int arr = 0; arr < 2; ++arr) {
        const float* A = arr ? A2 : A1;
        const uint16_t* W = arr ? wr : wl;
#pragma unroll
        for (int s = 0; s < 4; ++s) {
            int ko = s * 32 + g4 * 8;
            short8 a0h, a0l, a1h, a1l;
            cvt_hilo8(&A[(size_t)r0 * 128 + ko], a0h, a0l);
            cvt_hilo8(&A[(size_t)r1 * 128 + ko], a1h, a1l);
#pragma unroll
            for (int t = 0; t < 8; ++t) {
                int col = t * 16 + li;
                const uint16_t* p = &W[col * 128 + ko];
                short8 bh = *(const short8*)p;
                short8 bl = *(const short8*)(p + 16384);
                acc[0][t] = __builtin_amdgcn_mfma_f32_16x16x32_bf16(a0h, bh, acc[0][t], 0, 0, 0);
                acc[0][t] = __builtin_amdgcn_mfma_f32_16x16x32_bf16(a0l, bh, acc[0][t], 0, 0, 0);
                acc[0][t] = __builtin_amdgcn_mfma_f32_16x16x32_bf16(a0h, bl, acc[0][t], 0, 0, 0);
                acc[1][t] = __builtin_amdgcn_mfma_f32_16x16x32_bf16(a1h, bh, acc[1][t], 0, 0, 0);
                acc[1][t] = __builtin_amdgcn_mfma_f32_16x16x32_bf16(a1l, bh, acc[1][t], 0, 0, 0);
                acc[1][t] = __builtin_amdgcn_mfma_f32_16x16x32_bf16(a1h, bl, acc[1][t], 0, 0, 0);
            }
        }
    }
    // epilogue: bias + relu, f32 store.  D layout: col=lane&15, row=(lane>>4)*4+r
    int rowbase = blockIdx.x * 128 + wv * 32 + g4 * 4;
#pragma unroll
    for (int t = 0; t < 8; ++t) {
        int col = t * 16 + li;
        float bv = bias[col];
#pragma unroll
        for (int m = 0; m < 2; ++m) {
#pragma unroll
            for (int r = 0; r < 4; ++r) {
                int row = rowbase + m * 16 + r;
                if (row < N_NODES)
                    out[(size_t)row * 128 + col] = fmaxf(acc[m][t][r] + bv, 0.f);
            }
        }
    }
}

// -------- layer 2 GEMM fused with L2-normalize + log_softmax, out f32[N][47]
__global__ __launch_bounds__(256) void k_gemm2(const float* __restrict__ A1,
                                               const float* __restrict__ A2,
                                               const uint16_t* __restrict__ wl,
                                               const uint16_t* __restrict__ wr,
                                               const float* __restrict__ bias,
                                               float* __restrict__ out) {
    int tid = threadIdx.x;
    int lane = tid & 63, wv = tid >> 6;
    int li = lane & 15, g4 = lane >> 4;
    int mrow = blockIdx.x * 128 + wv * 32 + li;
    int r0 = min(mrow, N_NODES - 1);
    int r1 = min(mrow + 16, N_NODES - 1);

    f32x4 acc[2][3];
#pragma unroll
    for (int m = 0; m < 2; ++m)
#pragma unroll
        for (int t = 0; t < 3; ++t) acc[m][t] = (f32x4){0.f, 0.f, 0.f, 0.f};

#pragma unroll
    for (int arr = 0; arr < 2; ++arr) {
        const float* A = arr ? A2 : A1;
        const uint16_t* W = arr ? wr : wl;
#pragma unroll
        for (int s = 0; s < 4; ++s) {
            int ko = s * 32 + g4 * 8;
            short8 a0h, a0l, a1h, a1l;
            cvt_hilo8(&A[(size_t)r0 * 128 + ko], a0h, a0l);
            cvt_hilo8(&A[(size_t)r1 * 128 + ko], a1h, a1l);
#pragma unroll
            for (int t = 0; t < 3; ++t) {
                int col = t * 16 + li;
                const uint16_t* p = &W[col * 128 + ko];
                short8 bh = *(const short8*)p;
                short8 bl = *(const short8*)(p + 6144);
                acc[0][t] = __builtin_amdgcn_mfma_f32_16x16x32_bf16(a0h, bh, acc[0][t], 0, 0, 0);
                acc[0][t] = __builtin_amdgcn_mfma_f32_16x16x32_bf16(a0l, bh, acc[0][t], 0, 0, 0);
                acc[0][t] = __builtin_amdgcn_mfma_f32_16x16x32_bf16(a0h, bl, acc[0][t], 0, 0, 0);
                acc[1][t] = __builtin_amdgcn_mfma_f32_16x16x32_bf16(a1h, bh, acc[1][t], 0, 0, 0);
                acc[1][t] = __builtin_amdgcn_mfma_f32_16x16x32_bf16(a1l, bh, acc[1][t], 0, 0, 0);
                acc[1][t] = __builtin_amdgcn_mfma_f32_16x16x32_bf16(a1h, bl, acc[1][t], 0, 0, 0);
            }
        }
    }

    float b0 = bias[li];
    float b1 = bias[16 + li];
    bool v2ok = (li < 15);
    float b2 = v2ok ? bias[32 + li] : 0.f;

    int rowbase = blockIdx.x * 128 + wv * 32 + g4 * 4;
#pragma unroll
    for (int m = 0; m < 2; ++m) {
#pragma unroll
        for (int r = 0; r < 4; ++r) {
            int row = rowbase + m * 16 + r;
            float v0 = acc[m][0][r] + b0;
            float v1 = acc[m][1][r] + b1;
            float v2 = v2ok ? (acc[m][2][r] + b2) : 0.f;
            float ss = v0 * v0 + v1 * v1 + v2 * v2;
            ss += __shfl_xor(ss, 1);
            ss += __shfl_xor(ss, 2);
            ss += __shfl_xor(ss, 4);
            ss += __shfl_xor(ss, 8);
            float inv = 1.f / fmaxf(sqrtf(ss), 1e-12f);
            v0 *= inv; v1 *= inv; v2 *= inv;
            float mx = fmaxf(v0, v1);
            if (v2ok) mx = fmaxf(mx, v2);
            mx = fmaxf(mx, __shfl_xor(mx, 1));
            mx = fmaxf(mx, __shfl_xor(mx, 2));
            mx = fmaxf(mx, __shfl_xor(mx, 4));
            mx = fmaxf(mx, __shfl_xor(mx, 8));
            float se = expf(v0 - mx) + expf(v1 - mx) + (v2ok ? expf(v2 - mx) : 0.f);
            se += __shfl_xor(se, 1);
            se += __shfl_xor(se, 2);
            se += __shfl_xor(se, 4);
            se += __shfl_xor(se, 8);
            float lse = logf(se);
            if (row < N_NODES) {
                size_t ob = (size_t)row * NCLS;
                out[ob + li]      = v0 - mx - lse;
                out[ob + 16 + li] = v1 - mx - lse;
                if (v2ok) out[ob + 32 + li] = v2 - mx - lse;
            }
        }
    }
}

// ---------------------------------------------------------------------------
extern "C" void kernel_launch(void* const* d_in, const int* in_sizes, int n_in,
                              void* d_out, int out_size, void* d_ws, size_t ws_size,
                              hipStream_t stream) {
    const float* x   = (const float*)d_in[0];
    const int*   ei  = (const int*)d_in[1];
    const float* Wl0 = (const float*)d_in[2];
    const float* bl0 = (const float*)d_in[3];
    const float* Wr0 = (const float*)d_in[4];
    const float* Wl1 = (const float*)d_in[5];
    const float* bl1 = (const float*)d_in[6];
    const float* Wr1 = (const float*)d_in[7];
    const float* Wl2 = (const float*)d_in[8];
    const float* bl2 = (const float*)d_in[9];
    const float* Wr2 = (const float*)d_in[10];
    float* out = (float*)d_out;

    char* ws = (char*)d_ws;
    size_t cur = 0;
    auto alloc = [&](size_t bytes) {
        char* p = ws + cur;
        cur += (bytes + 255) & ~(size_t)255;
        return p;
    };
    int*      deg       = (int*)alloc(N_NODES * 4);
    int*      row_start = (int*)alloc(N_NODES * 4);
    int*      fill      = (int*)alloc(N_NODES * 4);
    float*    inv_deg   = (float*)alloc(N_NODES * 4);
    int*      src       = (int*)alloc(N_EDGES * 4);
    int*      dst       = (int*)alloc(N_EDGES * 4);
    int*      elist     = (int*)alloc(N_EDGES * 4);
    uint16_t* wimg      = (uint16_t*)alloc(155648 * 2);
    float*    bufA      = (float*)alloc((size_t)N_NODES * 128 * 4);
    float*    bufB      = (float*)alloc((size_t)N_NODES * 128 * 4);
    float*    bufC      = (float*)alloc((size_t)N_NODES * 128 * 4);

    hipMemsetAsync(deg, 0, N_NODES * 4, stream);
    k_prepw<<<6, 256, 0, stream>>>(Wl0, Wr0, Wl1, Wr1, Wl2, Wr2, wimg);

    int egrid = (N_EDGES + 255) / 256;
    k_cvt_idx<<<egrid, 256, 0, stream>>>(ei, src, dst);
    k_deg<<<egrid, 256, 0, stream>>>(dst, deg);
    k_scan<<<1, 1024, 0, stream>>>(deg, row_start, fill, inv_deg);
    k_fill<<<egrid, 256, 0, stream>>>(src, dst, fill, elist);

    int agrid = N_NODES / 4;                 // 12500
    int ggrid = (N_NODES + 127) / 128;       // 391

    // layer 0: agg(x) -> A; h0 = relu(A@Wl0 + x@Wr0 + b) -> B
    k_agg<<<agrid, 256, 0, stream>>>((const float2*)x, row_start, deg, inv_deg, elist, (float2*)bufA);
    k_gemm<<<ggrid, 256, 0, stream>>>(bufA, x, wimg, wimg + 32768, bl0, bufB);
    // layer 1: agg(h0) -> A; h1 = relu(A@Wl1 + h0@Wr1 + b) -> C
    k_agg<<<agrid, 256, 0, stream>>>((const float2*)bufB, row_start, deg, inv_deg, elist, (float2*)bufA);
    k_gemm<<<ggrid, 256, 0, stream>>>(bufA, bufB, wimg + 65536, wimg + 98304, bl1, bufC);
    // layer 2: agg(h1) -> B; out = logsoftmax(normalize(B@Wl2 + h1@Wr2 + b))
    k_agg<<<agrid, 256, 0, stream>>>((const float2*)bufC, row_start, deg, inv_deg, elist, (float2*)bufB);
    k_gemm2<<<ggrid, 256, 0, stream>>>(bufB, bufC, wimg + 131072, wimg + 143360, bl2, out);
}

// Round 4
// 435.685 us; speedup vs baseline: 1.5263x; 1.5263x over previous
//
#include <hip/hip_runtime.h>
#include <stdint.h>

#define N_NODES 50000
#define N_EDGES 600000
#define NCLS    47
#define SCAN_TPB 512
#define SCAN_BLOCKS ((N_NODES + SCAN_TPB - 1) / SCAN_TPB)   // 98

typedef __attribute__((ext_vector_type(8))) short short8;
typedef __attribute__((ext_vector_type(4))) float f32x4;

static __device__ __forceinline__ float bf2f(uint16_t h) {
    union { uint32_t u; float f; } c; c.u = ((uint32_t)h) << 16; return c.f;
}
static __device__ __forceinline__ uint16_t f2bf(float f) {
    union { float f; uint32_t u; } c; c.f = f;
    uint32_t u = c.u;
    return (uint16_t)((u + 0x7fffu + ((u >> 16) & 1u)) >> 16); // RNE
}
// split f32 -> bf16 hi + bf16 lo (v ~= hi + lo, err ~2^-18 rel)
static __device__ __forceinline__ void cvt_hilo8(const float* p, short8& hi, short8& lo) {
#pragma unroll
    for (int j = 0; j < 8; ++j) {
        float v = p[j];
        uint16_t h = f2bf(v);
        float r = v - bf2f(h);
        hi[j] = (short)h;
        lo[j] = (short)f2bf(r);
    }
}

// ---------- edge_index canonicalize (int64-or-int32 -> int32) + degree count
__global__ __launch_bounds__(256) void k_cvt_idx(const int* __restrict__ ei,
                                                 int* __restrict__ src,
                                                 int* __restrict__ dst,
                                                 int* __restrict__ deg) {
    __shared__ int is64;
    {
        int lane = threadIdx.x;
        if (lane < 64) {
            int f = ei[2 * lane + 1] | ei[2 * lane + 129]; // 128 hi-words if int64
            unsigned long long m = __ballot(f != 0);
            if (lane == 0) is64 = (m == 0ULL) ? 1 : 0;
        }
        __syncthreads();
    }
    int e = blockIdx.x * 256 + threadIdx.x;
    if (e < N_EDGES) {
        int s, d;
        if (is64) { s = ei[2 * e]; d = ei[2 * (N_EDGES + e)]; }
        else      { s = ei[e];     d = ei[N_EDGES + e]; }
        s = min(max(s, 0), N_NODES - 1);
        d = min(max(d, 0), N_NODES - 1);
        src[e] = s;
        dst[e] = d;
        atomicAdd(&deg[d], 1);
    }
}

// ------------------------------------------- scan stage 1: per-block partials
__global__ __launch_bounds__(SCAN_TPB) void k_scan1(const int* __restrict__ deg,
                                                    int* __restrict__ partial) {
    int t = blockIdx.x * SCAN_TPB + threadIdx.x;
    int v = (t < N_NODES) ? deg[t] : 0;
#pragma unroll
    for (int o = 1; o < 64; o <<= 1) v += __shfl_xor(v, o);
    __shared__ int ws[SCAN_TPB / 64];
    int lane = threadIdx.x & 63, w = threadIdx.x >> 6;
    if (lane == 0) ws[w] = v;
    __syncthreads();
    if (threadIdx.x == 0) {
        int s = 0;
#pragma unroll
        for (int i = 0; i < SCAN_TPB / 64; ++i) s += ws[i];
        partial[blockIdx.x] = s;
    }
}

// ---------------------------- scan stage 2: exclusive scan of 98 partials
__global__ __launch_bounds__(128) void k_scan2(int* __restrict__ partial) {
    __shared__ int sh[128];
    int t = threadIdx.x;
    int v = (t < SCAN_BLOCKS) ? partial[t] : 0;
    sh[t] = v;
    __syncthreads();
    for (int o = 1; o < 128; o <<= 1) {
        int u = (t >= o) ? sh[t - o] : 0;
        __syncthreads();
        sh[t] += u;
        __syncthreads();
    }
    if (t < SCAN_BLOCKS) partial[t] = sh[t] - v; // exclusive
}

// --------------- scan stage 3: block-local exclusive scan + offset, emit CSR
__global__ __launch_bounds__(SCAN_TPB) void k_scan3(const int* __restrict__ deg,
                                                    const int* __restrict__ partial,
                                                    int* __restrict__ row_start,
                                                    int* __restrict__ fill,
                                                    float* __restrict__ inv_deg) {
    int tb = threadIdx.x;
    int t = blockIdx.x * SCAN_TPB + tb;
    int v = (t < N_NODES) ? deg[t] : 0;
    int lane = tb & 63, w = tb >> 6;
    int inc = v;
#pragma unroll
    for (int o = 1; o < 64; o <<= 1) {
        int u = __shfl_up(inc, o);
        if (lane >= o) inc += u;
    }
    __shared__ int wsum[SCAN_TPB / 64];
    if (lane == 63) wsum[w] = inc;
    __syncthreads();
    int woff = 0;
    for (int i = 0; i < w; ++i) woff += wsum[i];
    int excl = partial[blockIdx.x] + woff + (inc - v);
    if (t < N_NODES) {
        row_start[t] = excl;
        fill[t] = excl;
        inv_deg[t] = 1.0f / (float)(v > 0 ? v : 1);
    }
}

// ---------------------------------------------------------------- bucket fill
__global__ __launch_bounds__(256) void k_fill(const int* __restrict__ src,
                                              const int* __restrict__ dst,
                                              int* __restrict__ fill,
                                              int* __restrict__ elist) {
    int e = blockIdx.x * 256 + threadIdx.x;
    if (e < N_EDGES) {
        int pos = atomicAdd(&fill[dst[e]], 1);
        elist[pos] = src[e];
    }
}

// ------------------------- mean aggregation (half-wave/node, float4, 4x MLP)
__global__ __launch_bounds__(256) void k_agg(const float4* __restrict__ hm,
                                             const int* __restrict__ row_start,
                                             const int* __restrict__ degv,
                                             const float* __restrict__ inv_deg,
                                             const int* __restrict__ elist,
                                             float4* __restrict__ aggm) {
    int l32 = threadIdx.x & 31;
    int node = blockIdx.x * 8 + (threadIdx.x >> 5);
    if (node >= N_NODES) return;
    int rs = row_start[node];
    int d = degv[node];
    float a0 = 0.f, a1 = 0.f, a2 = 0.f, a3 = 0.f;
    int i = 0;
    for (; i + 4 <= d; i += 4) {
        int s0 = elist[rs + i];
        int s1 = elist[rs + i + 1];
        int s2 = elist[rs + i + 2];
        int s3 = elist[rs + i + 3];
        float4 w0 = hm[(size_t)s0 * 32 + l32];
        float4 w1 = hm[(size_t)s1 * 32 + l32];
        float4 w2 = hm[(size_t)s2 * 32 + l32];
        float4 w3 = hm[(size_t)s3 * 32 + l32];
        a0 += (w0.x + w1.x) + (w2.x + w3.x);
        a1 += (w0.y + w1.y) + (w2.y + w3.y);
        a2 += (w0.z + w1.z) + (w2.z + w3.z);
        a3 += (w0.w + w1.w) + (w2.w + w3.w);
    }
    for (; i < d; ++i) {
        int s = elist[rs + i];
        float4 w = hm[(size_t)s * 32 + l32];
        a0 += w.x; a1 += w.y; a2 += w.z; a3 += w.w;
    }
    float sc = inv_deg[node];
    aggm[(size_t)node * 32 + l32] = make_float4(a0 * sc, a1 * sc, a2 * sc, a3 * sc);
}

// -------------- weight prep: transpose W[k][col] -> img[col][k], bf16 hi + lo
__global__ __launch_bounds__(256) void k_prepw(const float* Wl0, const float* Wr0,
                                               const float* Wl1, const float* Wr1,
                                               const float* Wl2, const float* Wr2,
                                               uint16_t* __restrict__ img) {
    int b = blockIdx.x;
    const float* W; int ncol, npad; uint16_t* o;
    switch (b) {
        case 0: W = Wl0; ncol = 128; npad = 128; o = img;           break;
        case 1: W = Wr0; ncol = 128; npad = 128; o = img + 32768;   break;
        case 2: W = Wl1; ncol = 128; npad = 128; o = img + 65536;   break;
        case 3: W = Wr1; ncol = 128; npad = 128; o = img + 98304;   break;
        case 4: W = Wl2; ncol = 47;  npad = 48;  o = img + 131072;  break;
        default:W = Wr2; ncol = 47;  npad = 48;  o = img + 143360;  break;
    }
    int elems = npad * 128;
    for (int i = threadIdx.x; i < elems; i += 256) {
        int col = i % npad, k = i / npad;
        float v = (col < ncol) ? W[k * ncol + col] : 0.f;
        uint16_t h = f2bf(v);
        uint16_t l = f2bf(v - bf2f(h));
        int idx = col * 128 + k;
        o[idx] = h;
        o[idx + elems] = l;
    }
}

// ----------------------------- GEMM layers 0/1: out = relu(A1@Wl + A2@Wr + b)
__global__ __launch_bounds__(256) void k_gemm(const float* __restrict__ A1,
                                              const float* __restrict__ A2,
                                              const uint16_t* __restrict__ wl,
                                              const uint16_t* __restrict__ wr,
                                              const float* __restrict__ bias,
                                              float* __restrict__ out) {
    int tid = threadIdx.x;
    int lane = tid & 63, wv = tid >> 6;
    int li = lane & 15, g4 = lane >> 4;
    int mrow = blockIdx.x * 128 + wv * 32 + li;
    int r0 = min(mrow, N_NODES - 1);
    int r1 = min(mrow + 16, N_NODES - 1);

    f32x4 acc[2][8];
#pragma unroll
    for (int m = 0; m < 2; ++m)
#pragma unroll
        for (int t = 0; t < 8; ++t) acc[m][t] = (f32x4){0.f, 0.f, 0.f, 0.f};

#pragma unroll
    for (int arr = 0; arr < 2; ++arr) {
        const float* A = arr ? A2 : A1;
        const uint16_t* W = arr ? wr : wl;
#pragma unroll
        for (int s = 0; s < 4; ++s) {
            int ko = s * 32 + g4 * 8;
            short8 a0h, a0l, a1h, a1l;
            cvt_hilo8(&A[(size_t)r0 * 128 + ko], a0h, a0l);
            cvt_hilo8(&A[(size_t)r1 * 128 + ko], a1h, a1l);
#pragma unroll
            for (int t = 0; t < 8; ++t) {
                int col = t * 16 + li;
                const uint16_t* p = &W[col * 128 + ko];
                short8 bh = *(const short8*)p;
                short8 bl = *(const short8*)(p + 16384);
                acc[0][t] = __builtin_amdgcn_mfma_f32_16x16x32_bf16(a0h, bh, acc[0][t], 0, 0, 0);
                acc[0][t] = __builtin_amdgcn_mfma_f32_16x16x32_bf16(a0l, bh, acc[0][t], 0, 0, 0);
                acc[0][t] = __builtin_amdgcn_mfma_f32_16x16x32_bf16(a0h, bl, acc[0][t], 0, 0, 0);
                acc[1][t] = __builtin_amdgcn_mfma_f32_16x16x32_bf16(a1h, bh, acc[1][t], 0, 0, 0);
                acc[1][t] = __builtin_amdgcn_mfma_f32_16x16x32_bf16(a1l, bh, acc[1][t], 0, 0, 0);
                acc[1][t] = __builtin_amdgcn_mfma_f32_16x16x32_bf16(a1h, bl, acc[1][t], 0, 0, 0);
            }
        }
    }
    int rowbase = blockIdx.x * 128 + wv * 32 + g4 * 4;
#pragma unroll
    for (int t = 0; t < 8; ++t) {
        int col = t * 16 + li;
        float bv = bias[col];
#pragma unroll
        for (int m = 0; m < 2; ++m) {
#pragma unroll
            for (int r = 0; r < 4; ++r) {
                int row = rowbase + m * 16 + r;
                if (row < N_NODES)
                    out[(size_t)row * 128 + col] = fmaxf(acc[m][t][r] + bv, 0.f);
            }
        }
    }
}

// -------- layer 2 GEMM fused with L2-normalize + log_softmax, out f32[N][47]
__global__ __launch_bounds__(256) void k_gemm2(const float* __restrict__ A1,
                                               const float* __restrict__ A2,
                                               const uint16_t* __restrict__ wl,
                                               const uint16_t* __restrict__ wr,
                                               const float* __restrict__ bias,
                                               float* __restrict__ out) {
    int tid = threadIdx.x;
    int lane = tid & 63, wv = tid >> 6;
    int li = lane & 15, g4 = lane >> 4;
    int mrow = blockIdx.x * 128 + wv * 32 + li;
    int r0 = min(mrow, N_NODES - 1);
    int r1 = min(mrow + 16, N_NODES - 1);

    f32x4 acc[2][3];
#pragma unroll
    for (int m = 0; m < 2; ++m)
#pragma unroll
        for (int t = 0; t < 3; ++t) acc[m][t] = (f32x4){0.f, 0.f, 0.f, 0.f};

#pragma unroll
    for (int arr = 0; arr < 2; ++arr) {
        const float* A = arr ? A2 : A1;
        const uint16_t* W = arr ? wr : wl;
#pragma unroll
        for (int s = 0; s < 4; ++s) {
            int ko = s * 32 + g4 * 8;
            short8 a0h, a0l, a1h, a1l;
            cvt_hilo8(&A[(size_t)r0 * 128 + ko], a0h, a0l);
            cvt_hilo8(&A[(size_t)r1 * 128 + ko], a1h, a1l);
#pragma unroll
            for (int t = 0; t < 3; ++t) {
                int col = t * 16 + li;
                const uint16_t* p = &W[col * 128 + ko];
                short8 bh = *(const short8*)p;
                short8 bl = *(const short8*)(p + 6144);
                acc[0][t] = __builtin_amdgcn_mfma_f32_16x16x32_bf16(a0h, bh, acc[0][t], 0, 0, 0);
                acc[0][t] = __builtin_amdgcn_mfma_f32_16x16x32_bf16(a0l, bh, acc[0][t], 0, 0, 0);
                acc[0][t] = __builtin_amdgcn_mfma_f32_16x16x32_bf16(a0h, bl, acc[0][t], 0, 0, 0);
                acc[1][t] = __builtin_amdgcn_mfma_f32_16x16x32_bf16(a1h, bh, acc[1][t], 0, 0, 0);
                acc[1][t] = __builtin_amdgcn_mfma_f32_16x16x32_bf16(a1l, bh, acc[1][t], 0, 0, 0);
                acc[1][t] = __builtin_amdgcn_mfma_f32_16x16x32_bf16(a1h, bl, acc[1][t], 0, 0, 0);
            }
        }
    }

    float b0 = bias[li];
    float b1 = bias[16 + li];
    bool v2ok = (li < 15);
    float b2 = v2ok ? bias[32 + li] : 0.f;

    int rowbase = blockIdx.x * 128 + wv * 32 + g4 * 4;
#pragma unroll
    for (int m = 0; m < 2; ++m) {
#pragma unroll
        for (int r = 0; r < 4; ++r) {
            int row = rowbase + m * 16 + r;
            float v0 = acc[m][0][r] + b0;
            float v1 = acc[m][1][r] + b1;
            float v2 = v2ok ? (acc[m][2][r] + b2) : 0.f;
            float ss = v0 * v0 + v1 * v1 + v2 * v2;
            ss += __shfl_xor(ss, 1);
            ss += __shfl_xor(ss, 2);
            ss += __shfl_xor(ss, 4);
            ss += __shfl_xor(ss, 8);
            float inv = 1.f / fmaxf(sqrtf(ss), 1e-12f);
            v0 *= inv; v1 *= inv; v2 *= inv;
            float mx = fmaxf(v0, v1);
            if (v2ok) mx = fmaxf(mx, v2);
            mx = fmaxf(mx, __shfl_xor(mx, 1));
            mx = fmaxf(mx, __shfl_xor(mx, 2));
            mx = fmaxf(mx, __shfl_xor(mx, 4));
            mx = fmaxf(mx, __shfl_xor(mx, 8));
            float se = expf(v0 - mx) + expf(v1 - mx) + (v2ok ? expf(v2 - mx) : 0.f);
            se += __shfl_xor(se, 1);
            se += __shfl_xor(se, 2);
            se += __shfl_xor(se, 4);
            se += __shfl_xor(se, 8);
            float lse = logf(se);
            if (row < N_NODES) {
                size_t ob = (size_t)row * NCLS;
                out[ob + li]      = v0 - mx - lse;
                out[ob + 16 + li] = v1 - mx - lse;
                if (v2ok) out[ob + 32 + li] = v2 - mx - lse;
            }
        }
    }
}

// ---------------------------------------------------------------------------
extern "C" void kernel_launch(void* const* d_in, const int* in_sizes, int n_in,
                              void* d_out, int out_size, void* d_ws, size_t ws_size,
                              hipStream_t stream) {
    const float* x   = (const float*)d_in[0];
    const int*   ei  = (const int*)d_in[1];
    const float* Wl0 = (const float*)d_in[2];
    const float* bl0 = (const float*)d_in[3];
    const float* Wr0 = (const float*)d_in[4];
    const float* Wl1 = (const float*)d_in[5];
    const float* bl1 = (const float*)d_in[6];
    const float* Wr1 = (const float*)d_in[7];
    const float* Wl2 = (const float*)d_in[8];
    const float* bl2 = (const float*)d_in[9];
    const float* Wr2 = (const float*)d_in[10];
    float* out = (float*)d_out;

    char* ws = (char*)d_ws;
    size_t cur = 0;
    auto alloc = [&](size_t bytes) {
        char* p = ws + cur;
        cur += (bytes + 255) & ~(size_t)255;
        return p;
    };
    int*      deg       = (int*)alloc(N_NODES * 4);
    int*      row_start = (int*)alloc(N_NODES * 4);
    int*      fill      = (int*)alloc(N_NODES * 4);
    float*    inv_deg   = (float*)alloc(N_NODES * 4);
    int*      partial   = (int*)alloc(SCAN_BLOCKS * 4);
    int*      src       = (int*)alloc(N_EDGES * 4);
    int*      dst       = (int*)alloc(N_EDGES * 4);
    int*      elist     = (int*)alloc(N_EDGES * 4);
    uint16_t* wimg      = (uint16_t*)alloc(155648 * 2);
    float*    bufA      = (float*)alloc((size_t)N_NODES * 128 * 4);
    float*    bufB      = (float*)alloc((size_t)N_NODES * 128 * 4);
    float*    bufC      = (float*)alloc((size_t)N_NODES * 128 * 4);

    hipMemsetAsync(deg, 0, N_NODES * 4, stream);
    k_prepw<<<6, 256, 0, stream>>>(Wl0, Wr0, Wl1, Wr1, Wl2, Wr2, wimg);

    int egrid = (N_EDGES + 255) / 256;
    k_cvt_idx<<<egrid, 256, 0, stream>>>(ei, src, dst, deg);
    k_scan1<<<SCAN_BLOCKS, SCAN_TPB, 0, stream>>>(deg, partial);
    k_scan2<<<1, 128, 0, stream>>>(partial);
    k_scan3<<<SCAN_BLOCKS, SCAN_TPB, 0, stream>>>(deg, partial, row_start, fill, inv_deg);
    k_fill<<<egrid, 256, 0, stream>>>(src, dst, fill, elist);

    int agrid = (N_NODES + 7) / 8;           // 6250
    int ggrid = (N_NODES + 127) / 128;       // 391

    // layer 0: agg(x) -> A; h0 = relu(A@Wl0 + x@Wr0 + b) -> B
    k_agg<<<agrid, 256, 0, stream>>>((const float4*)x, row_start, deg, inv_deg, elist, (float4*)bufA);
    k_gemm<<<ggrid, 256, 0, stream>>>(bufA, x, wimg, wimg + 32768, bl0, bufB);
    // layer 1: agg(h0) -> A; h1 = relu(A@Wl1 + h0@Wr1 + b) -> C
    k_agg<<<agrid, 256, 0, stream>>>((const float4*)bufB, row_start, deg, inv_deg, elist, (float4*)bufA);
    k_gemm<<<ggrid, 256, 0, stream>>>(bufA, bufB, wimg + 65536, wimg + 98304, bl1, bufC);
    // layer 2: agg(h1) -> B; out = logsoftmax(normalize(B@Wl2 + h1@Wr2 + b))
    k_agg<<<agrid, 256, 0, stream>>>((const float4*)bufC, row_start, deg, inv_deg, elist, (float4*)bufB);
    k_gemm2<<<ggrid, 256, 0, stream>>>(bufB, bufC, wimg + 131072, wimg + 143360, bl2, out);
}